// Round 14
// baseline (158.311 us; speedup 1.0000x reference)
//
#include <hip/hip_runtime.h>

// Camera back-projection R14: R13 champion, 512-thread blocks / 64-iz chunks.
//
// Same data flow as R13 (~46us kernel): in-block bit-exact tables in LDS,
// lanes = 16ix x 4iy (row-riding gathers), LDS-transposed iz-contiguous
// stores, pipelined gathers across the store phase, slab-major write
// ordering, XCD-local depth. R14 changes the block shape only:
//   - 512 threads, 2 chunks of 64 iz (was 256 threads, 4 chunks of 32):
//     barriers/block 9 -> 5 (each barrier drains lgkm/vm across the block),
//     store wave-instr covers 4 x 256B pieces (was 8 x 128B) = 2x DRAM run,
//     tables prologue 5 divs/thread (was 10).
//   - LDS 23.9KB x 4 blocks/CU = 95KB; 4 x 8 waves = 32 waves/CU unchanged.
//
// Numerics (absmax 0.0 every round): exact IEEE '/' + rintf half-to-even in
// the reference's op order; U = ui<<2|uok<<15 (ushort), V = vi*1920|vok<<31;
// offset = ((U&0x7FFF)+V)&0xFFFFF, valid = sign(V & U<<16); epilogue
// max(fma(-128,|zc-d|,1),0) == 1-128*min(|zc-d|,1/128) exactly; zc via exact
// fma; d>0 folds into the truncation branch (zc >= 1.70).

#define RES  128
#define IMG  480
#define TS   68     // result tile row stride (floats), 64 iz + 4 pad
#define US   136    // U slab row stride (ushorts)
#define VS   132    // V slab row stride (uints)

template<int C>
__device__ __forceinline__ void compute_chunk(
    float* __restrict__ r,
    const unsigned short* __restrict__ sU,
    const unsigned* __restrict__ sV,
    const char* __restrict__ dbase,
    float cd, int ix_l, int iy_l, int w)
{
#pragma unroll
    for (int g = 0; g < 2; ++g) {
        const int jq  = w * 2 + g;           // iz quad slot (0..15)
        const int izc = C * 64 + jq * 4;     // global iz of quad
        const ushort4 pu4 = *(const ushort4*)&sU[ix_l * US + izc];
        const uint4   pv4 = *(const uint4*)&sV[iy_l * VS + izc];
        const unsigned pua[4] = {pu4.x, pu4.y, pu4.z, pu4.w};
        const unsigned pva[4] = {pv4.x, pv4.y, pv4.z, pv4.w};
#pragma unroll
        for (int j = 0; j < 4; ++j) {
            const int   iz = izc + j;
            const float z  = fmaf((float)iz + 0.5f, 0.0078125f, -0.5f); // exact
            const float zc = cd - z;
            const unsigned off = ((pua[j] & 0x7FFFu) + pva[j]) & 0xFFFFFu;
            const float d  = *(const float*)(dbase + off);   // cache-hot gather
            const bool ok  = (int)(pva[j] & (pua[j] << 16)) < 0;
            const float v  = fmaxf(fmaf(-128.0f, fabsf(zc - d), 1.0f), 0.0f);
            r[g * 4 + j] = ok ? v : 0.0f;
        }
    }
}

__global__ __launch_bounds__(512, 8) void cbp_main(
    const float* __restrict__ depth, const float* __restrict__ fl,
    const float* __restrict__ cam_dist, float* __restrict__ out, int N)
{
    __shared__ __align__(16) float          s_tile[64 * TS];  // 17,408 B
    __shared__ __align__(16) unsigned short s_U[16 * US];     //  4,352 B
    __shared__ __align__(16) unsigned       s_V[4 * VS];      //  2,112 B

    const int b = blockIdx.x;
    int n, rblk;
    if (N == 16) {                  // XCD-local: 2 depth images per XCD's L2
        const int xcd = b & 7, i = b >> 3;
        n = xcd * 2 + (i >> 8);
        rblk = i & 255;
    } else { n = b >> 8; rblk = b & 255; }
    const int ixg = rblk >> 5;      // 16-ix group (0..7), slab-major:
    const int iyg = rblk & 31;      // concurrent blocks tile one 1MB ix-slab
    const int l   = threadIdx.x;
    const float flv = fl[n];
    const float cd  = cam_dist[n];

    // ---- in-block tables: 5 exact IEEE divisions per thread ----
#pragma unroll
    for (int k = 0; k < 4; ++k) {   // U slab: 16 ix rows x 128 iz
        const int e   = l + 512 * k;
        const int row = e >> 7, izt = e & 127;
        const float zc = cd - ((izt + 0.5f) / 128.0f - 0.5f);
        const float x  = (ixg * 16 + row + 0.5f) / 128.0f - 0.5f;
        const float u  = (flv * x) / zc + 239.5f;            // exact IEEE div
        const int   ui = (int)fminf(fmaxf(rintf(u), 0.0f), 479.0f);
        const unsigned uok = (u >= 0.0f) && (u <= 479.0f);
        s_U[row * US + izt] = (unsigned short)((ui << 2) | (uok << 15));
    }
    {   // V slab: 4 iy rows x 128 iz (512 entries, one per thread)
        const int iyt = l >> 7, izt = l & 127;
        const float zc = cd - ((izt + 0.5f) / 128.0f - 0.5f);
        const float y  = (iyg * 4 + iyt + 0.5f) / 128.0f - 0.5f;
        const float v  = (flv * y) / zc + 239.5f;            // exact IEEE div
        const int   vi = (int)fminf(fmaxf(rintf(v), 0.0f), 479.0f);
        const unsigned vok = (v >= 0.0f) && (v <= 479.0f) && (zc > 0.0f);
        s_V[iyt * VS + izt] = (unsigned)(vi * (IMG * 4)) | (vok << 31);
    }
    __syncthreads();

    const int ix_l = l & 15, iy_l = (l >> 4) & 3, w = l >> 6;  // w: 0..7
    const int trow = ix_l * 4 + iy_l;
    const char* __restrict__ dbase = (const char*)(depth + (size_t)n * (IMG * IMG));
    const size_t obase = ((size_t)((n << 7) + ixg * 16) << 7 | (iyg * 4)) << 7;

    float r[8];                     // pipelined chunk results (2 float4)
    compute_chunk<0>(r, s_U, s_V, dbase, cd, ix_l, iy_l, w);

#pragma unroll
    for (int c = 0; c < 2; ++c) {
        __syncthreads();            // tile free (prev store-phase reads done)
        *(float4*)&s_tile[trow * TS + (w * 2) * 4]     = *(const float4*)&r[0];
        *(float4*)&s_tile[trow * TS + (w * 2 + 1) * 4] = *(const float4*)&r[4];
        __syncthreads();            // tile full

        // issue next chunk's gathers; they overlap the store phase below
        if (c == 0) compute_chunk<1>(r, s_U, s_V, dbase, cd, ix_l, iy_l, w);

        // store: 2 float4/thread; wave instr = 4 x 256B contiguous pieces
#pragma unroll
        for (int s = 0; s < 2; ++s) {
            const int f  = l + 512 * s;          // 0..1023
            const int rw = f >> 4, q = f & 15;   // tile row, iz quad in chunk
            const float4 val = *(const float4*)&s_tile[rw * TS + q * 4];
            const int ix2 = rw >> 2, iy2 = rw & 3;
            *(float4*)&out[obase + ((size_t)ix2 << 14) + (iy2 << 7) + c * 64 + q * 4] = val;
        }
    }
}

extern "C" void kernel_launch(void* const* d_in, const int* in_sizes, int n_in,
                              void* d_out, int out_size, void* d_ws, size_t ws_size,
                              hipStream_t stream) {
    const float* depth = (const float*)d_in[0];
    const float* fl    = (const float*)d_in[1];
    const float* cd    = (const float*)d_in[2];
    float* out         = (float*)d_out;

    const int N = in_sizes[1];                     // fl is (N,1)
    cbp_main<<<N * 256, 512, 0, stream>>>(depth, fl, cd, out, N);
}